// Round 8
// baseline (443.536 us; speedup 1.0000x reference)
//
#include <hip/hip_runtime.h>

#define BN_EPS 1e-5f
#define BSH 8  // 256 dsts per bucket

typedef __attribute__((ext_vector_type(8))) short bf16x8;
typedef __attribute__((ext_vector_type(4))) float f32x4;

__device__ inline float bfhi(unsigned int v) { return __uint_as_float(v & 0xFFFF0000u); }
__device__ inline float bflo(unsigned int v) { return __uint_as_float(v << 16); }
__device__ inline unsigned short f2bf(float f) {
  unsigned int u = __float_as_uint(f);
  u += 0x7FFFu + ((u >> 16) & 1u);  // RNE
  return (unsigned short)(u >> 16);
}
__device__ inline unsigned int pack2bf(float lo, float hi) {
  return (unsigned int)f2bf(lo) | ((unsigned int)f2bf(hi) << 16);
}

// ---------------- binned CSR build + input conversions (merged grid) ----------------
__global__ void k_prep(const int* __restrict__ src, const int* __restrict__ dst,
                       int* __restrict__ gcur, uint2* __restrict__ sedge,
                       int NB, int CAP, int E, int BB,
                       const float* __restrict__ x, const float* __restrict__ W0,
                       const float* __restrict__ W1, const float* __restrict__ W2,
                       unsigned short* __restrict__ xb, unsigned short* __restrict__ Wt0,
                       unsigned short* __restrict__ Wt1, unsigned short* __restrict__ Wt2,
                       int n) {
  if ((int)blockIdx.x < BB) {
    // ---- bucket part: localized sedge writes (bucket-contiguous) ----
    __shared__ int lh[512], rb[512];
    int tid = threadIdx.x;
    for (int i = tid; i < NB; i += 256) lh[i] = 0;
    __syncthreads();
    int base = blockIdx.x * 8192;
    int lim = min(8192, E - base);
    for (int i = tid; i < lim; i += 256)
      atomicAdd(&lh[dst[base + i] >> BSH], 1);
    __syncthreads();
    for (int i = tid; i < NB; i += 256) {
      int c = lh[i];
      rb[i] = c ? atomicAdd(&gcur[i], c) : 0;
      lh[i] = 0;
    }
    __syncthreads();
    for (int i = tid; i < lim; i += 256) {
      int d = dst[base + i];
      int s = src[base + i];
      int b = d >> BSH;
      int pos = rb[b] + atomicAdd(&lh[b], 1);
      if (pos < CAP) {
        uint2 v; v.x = (unsigned int)s; v.y = (unsigned int)d;
        sedge[(size_t)b * CAP + pos] = v;
      }
    }
  } else {
    // ---- conversion part (4 elems/thread) ----
    int t0 = (((int)blockIdx.x - BB) * 256 + (int)threadIdx.x) * 4;
#pragma unroll
    for (int u = 0; u < 4; ++u) {
      int t = t0 + u;
      if (t < 4096) {                       // Wt0 [128][32] <- W0 [30][128]
        int nn = t >> 5, k = t & 31;
        Wt0[t] = f2bf(k < 30 ? W0[k * 128 + nn] : 0.f);
      } else if (t < 20480) {               // Wt1 [128][128]
        int i = t - 4096; int nn = i >> 7, k = i & 127;
        Wt1[i] = f2bf(W1[k * 128 + nn]);
      } else if (t < 36864) {               // Wt2
        int i = t - 20480; int nn = i >> 7, k = i & 127;
        Wt2[i] = f2bf(W2[k * 128 + nn]);
      } else {                              // xbf [n][32] <- x [n][30]
        int i = t - 36864;
        if (i < n * 32) {
          int row = i >> 5, c = i & 31;
          xb[i] = f2bf(c < 30 ? x[row * 30 + c] : 0.f);
        }
      }
    }
  }
}

// 1024 threads/block: 4x stream parallelism on the 391-block grid
__global__ void k_csr1(const uint2* __restrict__ sedge, const int* __restrict__ gcur,
                       int* __restrict__ startv, int* __restrict__ cnt,
                       float* __restrict__ dinv, int CAP, int n) {
  int b = blockIdx.x, tid = threadIdx.x;
  __shared__ int h[256], sc[256];
  if (tid < 256) h[tid] = 0;
  __syncthreads();
  int cb = gcur[b]; if (cb > CAP) cb = CAP;
  const uint2* sd = sedge + (size_t)b * CAP;
  for (int i = tid; i < cb; i += 1024) atomicAdd(&h[sd[i].y & 255], 1);
  __syncthreads();
  if (tid < 256) sc[tid] = h[tid];
  __syncthreads();
  for (int o = 1; o < 256; o <<= 1) {
    int t = (tid < 256 && tid >= o) ? sc[tid - o] : 0;
    __syncthreads();
    if (tid < 256) sc[tid] += t;
    __syncthreads();
  }
  if (tid < 256) {
    int gd = (b << BSH) + tid;
    if (gd < n) {
      int v = h[tid];
      startv[gd] = b * CAP + (sc[tid] - v);
      cnt[gd] = v;
      dinv[gd] = rsqrtf((float)v + 1.0f);
    }
  }
}

// elist entry: src (17 bits) | round(dinv[src]*32767) (15 bits); 1024 threads
__global__ void k_csr2(const uint2* __restrict__ sedge, const int* __restrict__ gcur,
                       const int* __restrict__ startv, const float* __restrict__ dinv,
                       unsigned int* __restrict__ elist, int CAP, int n) {
  int b = blockIdx.x, tid = threadIdx.x;
  __shared__ int cur[256];
  if (tid < 256) {
    int gd = (b << BSH) + tid;
    cur[tid] = (gd < n) ? startv[gd] : 0;
  }
  __syncthreads();
  int cb = gcur[b]; if (cb > CAP) cb = CAP;
  const uint2* sd = sedge + (size_t)b * CAP;
  for (int i = tid; i < cb; i += 1024) {
    uint2 e = sd[i];
    int pos = atomicAdd(&cur[e.y & 255], 1);
    unsigned int u = (unsigned int)(dinv[e.x] * 32767.0f + 0.5f);
    elist[pos] = e.x | (u << 17);
  }
}

// ---------------- layer-0 gather on x [n,32] bf16 (64 B rows); 16 rows/block ----------------
__global__ void k_gather0(const unsigned int* __restrict__ elist, const int* __restrict__ start,
                          const int* __restrict__ cnt, const float* __restrict__ dinv,
                          const uint4* __restrict__ x4,  // [n,4] uint4 (row = 32 bf16)
                          unsigned int* __restrict__ G0, int n) {
  int lane = threadIdx.x & 63;
  int wv   = threadIdx.x >> 6;   // 0..15
  int grp  = lane >> 2;          // 0..15 edge slot
  int q4   = lane & 3;           // col chunk
  int row  = blockIdx.x * 16 + wv;
  bool active = row < n;

  float acc[8];
  float di = 0.f, dq = 0.f;
  int len = 0;
  const unsigned int* ep = elist;
  if (active) {
    di = dinv[row];
    dq = di * (1.0f / 32767.0f);
    len = cnt[row];
    ep = elist + start[row];
  }
  {
    float selfw = (grp == 0 && active) ? di * di : 0.f;
    uint4 hv = (grp == 0 && active) ? x4[(size_t)row * 4 + q4] : make_uint4(0, 0, 0, 0);
    acc[0] = bflo(hv.x) * selfw; acc[1] = bfhi(hv.x) * selfw;
    acc[2] = bflo(hv.y) * selfw; acc[3] = bfhi(hv.y) * selfw;
    acc[4] = bflo(hv.z) * selfw; acc[5] = bfhi(hv.z) * selfw;
    acc[6] = bflo(hv.w) * selfw; acc[7] = bfhi(hv.w) * selfw;
  }
  int j = 0;
  for (; j + 32 <= len; j += 32) {
    unsigned int e0 = ep[j + grp];
    unsigned int e1 = ep[j + 16 + grp];
    uint4 v0 = x4[(size_t)(e0 & 0x1FFFFu) * 4 + q4];
    uint4 v1 = x4[(size_t)(e1 & 0x1FFFFu) * 4 + q4];
    float w0 = (float)(e0 >> 17) * dq;
    float w1 = (float)(e1 >> 17) * dq;
    acc[0] = fmaf(bflo(v0.x), w0, acc[0]); acc[1] = fmaf(bfhi(v0.x), w0, acc[1]);
    acc[2] = fmaf(bflo(v0.y), w0, acc[2]); acc[3] = fmaf(bfhi(v0.y), w0, acc[3]);
    acc[4] = fmaf(bflo(v0.z), w0, acc[4]); acc[5] = fmaf(bfhi(v0.z), w0, acc[5]);
    acc[6] = fmaf(bflo(v0.w), w0, acc[6]); acc[7] = fmaf(bfhi(v0.w), w0, acc[7]);
    acc[0] = fmaf(bflo(v1.x), w1, acc[0]); acc[1] = fmaf(bfhi(v1.x), w1, acc[1]);
    acc[2] = fmaf(bflo(v1.y), w1, acc[2]); acc[3] = fmaf(bfhi(v1.y), w1, acc[3]);
    acc[4] = fmaf(bflo(v1.z), w1, acc[4]); acc[5] = fmaf(bfhi(v1.z), w1, acc[5]);
    acc[6] = fmaf(bflo(v1.w), w1, acc[6]); acc[7] = fmaf(bfhi(v1.w), w1, acc[7]);
  }
  for (; j < len; j += 16) {
    int jj = j + grp;
    unsigned int e = (jj < len) ? ep[jj] : 0u;   // e==0 -> w==0, harmless row-0 load
    uint4 v = x4[(size_t)(e & 0x1FFFFu) * 4 + q4];
    float w = (float)(e >> 17) * dq;
    acc[0] = fmaf(bflo(v.x), w, acc[0]); acc[1] = fmaf(bfhi(v.x), w, acc[1]);
    acc[2] = fmaf(bflo(v.y), w, acc[2]); acc[3] = fmaf(bfhi(v.y), w, acc[3]);
    acc[4] = fmaf(bflo(v.z), w, acc[4]); acc[5] = fmaf(bfhi(v.z), w, acc[5]);
    acc[6] = fmaf(bflo(v.w), w, acc[6]); acc[7] = fmaf(bfhi(v.w), w, acc[7]);
  }
#pragma unroll
  for (int k = 0; k < 8; ++k) {
    acc[k] += __shfl_xor(acc[k], 4);
    acc[k] += __shfl_xor(acc[k], 8);
    acc[k] += __shfl_xor(acc[k], 16);
    acc[k] += __shfl_xor(acc[k], 32);
  }
  if (grp == 0 && active) {
    uint4 o;
    o.x = pack2bf(acc[0], acc[1]);
    o.y = pack2bf(acc[2], acc[3]);
    o.z = pack2bf(acc[4], acc[5]);
    o.w = pack2bf(acc[6], acc[7]);
    ((uint4*)G0)[(size_t)row * 4 + q4] = o;  // 32 bf16 = 4 uint4 per row
  }
}

// ---------------- MFMA GEMM: fused BN on A computed in-prologue from slabs ----------------
// No fences: bnIn slab was completed by a PREVIOUS kernel on the stream.
__global__ void k_gemm_mfma(const unsigned short* __restrict__ A,
                            const unsigned short* __restrict__ Wt,
                            const float* __restrict__ bnIn, const float* __restrict__ gamma,
                            const float* __restrict__ beta, int doBN,
                            const float* __restrict__ bias, float* __restrict__ bnslab,
                            int doStats, unsigned short* __restrict__ C, int n, int Kp) {
  __shared__ float ssc[128], ssh[128];
  if (doBN) {
    __shared__ float red[256];
    int tid = threadIdx.x;
    int which = tid >> 7, c = tid & 127;
    float s = 0.f;
    for (int k = 0; k < 64; ++k) s += bnIn[k * 256 + which * 128 + c];
    red[tid] = s;
    __syncthreads();
    if (tid < 128) {
      float invn = 1.0f / (float)n;
      float mu  = red[tid] * invn;
      float var = fmaxf(red[128 + tid] * invn - mu * mu, 0.f);
      float sc  = gamma[tid] * rsqrtf(var + BN_EPS);
      ssc[tid] = sc;
      ssh[tid] = fmaf(-mu, sc, beta[tid]);
    }
    __syncthreads();
  }
  int wave = threadIdx.x >> 6;
  int lane = threadIdx.x & 63;
  int m0 = blockIdx.x * 128 + wave * 32;  // always < Npad; no early return (stats barrier)
  int lm = lane & 15;
  int lq = lane >> 4;

  f32x4 acc[2][8] = {};
  const unsigned short* Arow0 = A + (size_t)(m0 + lm) * Kp + lq * 8;
  const unsigned short* Arow1 = Arow0 + (size_t)16 * Kp;
  const unsigned short* Bbase = Wt + (size_t)lm * Kp + lq * 8;

  for (int k0 = 0; k0 < Kp; k0 += 32) {
    uint4 ra0 = *(const uint4*)(Arow0 + k0);
    uint4 ra1 = *(const uint4*)(Arow1 + k0);
    bf16x8 a0, a1;
    if (doBN) {
      int cb = k0 + lq * 8;
      unsigned int w0 = pack2bf(fmaxf(fmaf(bflo(ra0.x), ssc[cb+0], ssh[cb+0]), 0.f),
                                fmaxf(fmaf(bfhi(ra0.x), ssc[cb+1], ssh[cb+1]), 0.f));
      unsigned int w1 = pack2bf(fmaxf(fmaf(bflo(ra0.y), ssc[cb+2], ssh[cb+2]), 0.f),
                                fmaxf(fmaf(bfhi(ra0.y), ssc[cb+3], ssh[cb+3]), 0.f));
      unsigned int w2 = pack2bf(fmaxf(fmaf(bflo(ra0.z), ssc[cb+4], ssh[cb+4]), 0.f),
                                fmaxf(fmaf(bfhi(ra0.z), ssc[cb+5], ssh[cb+5]), 0.f));
      unsigned int w3 = pack2bf(fmaxf(fmaf(bflo(ra0.w), ssc[cb+6], ssh[cb+6]), 0.f),
                                fmaxf(fmaf(bfhi(ra0.w), ssc[cb+7], ssh[cb+7]), 0.f));
      uint4 pa0 = make_uint4(w0, w1, w2, w3);
      a0 = *(bf16x8*)&pa0;
      unsigned int y0 = pack2bf(fmaxf(fmaf(bflo(ra1.x), ssc[cb+0], ssh[cb+0]), 0.f),
                                fmaxf(fmaf(bfhi(ra1.x), ssc[cb+1], ssh[cb+1]), 0.f));
      unsigned int y1 = pack2bf(fmaxf(fmaf(bflo(ra1.y), ssc[cb+2], ssh[cb+2]), 0.f),
                                fmaxf(fmaf(bfhi(ra1.y), ssc[cb+3], ssh[cb+3]), 0.f));
      unsigned int y2 = pack2bf(fmaxf(fmaf(bflo(ra1.z), ssc[cb+4], ssh[cb+4]), 0.f),
                                fmaxf(fmaf(bfhi(ra1.z), ssc[cb+5], ssh[cb+5]), 0.f));
      unsigned int y3 = pack2bf(fmaxf(fmaf(bflo(ra1.w), ssc[cb+6], ssh[cb+6]), 0.f),
                                fmaxf(fmaf(bfhi(ra1.w), ssc[cb+7], ssh[cb+7]), 0.f));
      uint4 pa1 = make_uint4(y0, y1, y2, y3);
      a1 = *(bf16x8*)&pa1;
    } else {
      a0 = *(bf16x8*)&ra0;
      a1 = *(bf16x8*)&ra1;
    }
#pragma unroll
    for (int t = 0; t < 8; ++t) {
      bf16x8 b = *(const bf16x8*)(Bbase + (size_t)t * 16 * Kp + k0);
      acc[0][t] = __builtin_amdgcn_mfma_f32_16x16x32_bf16(a0, b, acc[0][t], 0, 0, 0);
      acc[1][t] = __builtin_amdgcn_mfma_f32_16x16x32_bf16(a1, b, acc[1][t], 0, 0, 0);
    }
  }

#pragma unroll
  for (int h = 0; h < 2; ++h) {
    int rbase = m0 + h * 16 + lq * 4;
#pragma unroll
    for (int t = 0; t < 8; ++t) {
      int col = t * 16 + lm;
      float bv = doStats ? bias[col] : 0.f;
#pragma unroll
      for (int r = 0; r < 4; ++r) {
        int row = rbase + r;
        if (row < n) C[(size_t)row * 128 + col] = f2bf(acc[h][t][r] + bv);
      }
    }
  }

  if (doStats) {
    __shared__ float sms[4][256];
#pragma unroll
    for (int t = 0; t < 8; ++t) {
      int col = t * 16 + lm;
      float bv = bias[col];
      float s = 0.f, s2 = 0.f;
#pragma unroll
      for (int h = 0; h < 2; ++h) {
        int rbase = m0 + h * 16 + lq * 4;
#pragma unroll
        for (int r = 0; r < 4; ++r) {
          if (rbase + r < n) {
            float v = acc[h][t][r] + bv;
            s += v; s2 = fmaf(v, v, s2);
          }
        }
      }
      s  += __shfl_xor(s, 16);  s  += __shfl_xor(s, 32);
      s2 += __shfl_xor(s2, 16); s2 += __shfl_xor(s2, 32);
      if (lq == 0) { sms[wave][col] = s; sms[wave][128 + col] = s2; }
    }
    __syncthreads();
    int tid = threadIdx.x;
    int slab = (blockIdx.x & 63) * 256;
    float tot = sms[0][tid] + sms[1][tid] + sms[2][tid] + sms[3][tid];
    atomicAdd(&bnslab[slab + tid], tot);
  }
}

// ---------------- CSR gather (layers 1-2), wave-per-row, 16 rows/block ----------------
__global__ void k_gather(const unsigned int* __restrict__ elist, const int* __restrict__ start,
                         const int* __restrict__ cnt, const float* __restrict__ dinv,
                         const uint4* __restrict__ h4,  // [n,16] uint4 (row = 128 bf16)
                         const float* __restrict__ bias, unsigned int* __restrict__ agg,
                         float* __restrict__ bnsumP, int n) {
  int lane = threadIdx.x & 63;
  int wv   = threadIdx.x >> 6;   // 0..15
  int grp  = lane >> 4;
  int c8   = lane & 15;
  int row  = blockIdx.x * 16 + wv;
  bool active = row < n;

  float acc[8];
  float di = 0.f, dq = 0.f;
  int len = 0;
  const unsigned int* ep = elist;

  if (active) {
    di = dinv[row];
    dq = di * (1.0f / 32767.0f);
    len = cnt[row];
    ep = elist + start[row];
  }

  {
    float selfw = (grp == 0 && active) ? di * di : 0.f;
    float4 b0 = make_float4(0.f, 0.f, 0.f, 0.f), b1 = b0;
    if (grp == 0 && active) {
      b0 = ((const float4*)bias)[c8 * 2];
      b1 = ((const float4*)bias)[c8 * 2 + 1];
    }
    uint4 hv = active ? h4[(size_t)row * 16 + c8] : make_uint4(0, 0, 0, 0);
    acc[0] = fmaf(bflo(hv.x), selfw, b0.x);
    acc[1] = fmaf(bfhi(hv.x), selfw, b0.y);
    acc[2] = fmaf(bflo(hv.y), selfw, b0.z);
    acc[3] = fmaf(bfhi(hv.y), selfw, b0.w);
    acc[4] = fmaf(bflo(hv.z), selfw, b1.x);
    acc[5] = fmaf(bfhi(hv.z), selfw, b1.y);
    acc[6] = fmaf(bflo(hv.w), selfw, b1.z);
    acc[7] = fmaf(bfhi(hv.w), selfw, b1.w);
  }

  int j = 0;
  for (; j + 16 <= len; j += 16) {
    unsigned int e0 = ep[j + grp];
    unsigned int e1 = ep[j + 4 + grp];
    unsigned int e2 = ep[j + 8 + grp];
    unsigned int e3 = ep[j + 12 + grp];
    uint4 v0 = h4[(size_t)(e0 & 0x1FFFFu) * 16 + c8];
    uint4 v1 = h4[(size_t)(e1 & 0x1FFFFu) * 16 + c8];
    uint4 v2 = h4[(size_t)(e2 & 0x1FFFFu) * 16 + c8];
    uint4 v3 = h4[(size_t)(e3 & 0x1FFFFu) * 16 + c8];
    float w0 = (float)(e0 >> 17) * dq;
    float w1 = (float)(e1 >> 17) * dq;
    float w2 = (float)(e2 >> 17) * dq;
    float w3 = (float)(e3 >> 17) * dq;
    acc[0] = fmaf(bflo(v0.x), w0, acc[0]); acc[1] = fmaf(bfhi(v0.x), w0, acc[1]);
    acc[2] = fmaf(bflo(v0.y), w0, acc[2]); acc[3] = fmaf(bfhi(v0.y), w0, acc[3]);
    acc[4] = fmaf(bflo(v0.z), w0, acc[4]); acc[5] = fmaf(bfhi(v0.z), w0, acc[5]);
    acc[6] = fmaf(bflo(v0.w), w0, acc[6]); acc[7] = fmaf(bfhi(v0.w), w0, acc[7]);
    acc[0] = fmaf(bflo(v1.x), w1, acc[0]); acc[1] = fmaf(bfhi(v1.x), w1, acc[1]);
    acc[2] = fmaf(bflo(v1.y), w1, acc[2]); acc[3] = fmaf(bfhi(v1.y), w1, acc[3]);
    acc[4] = fmaf(bflo(v1.z), w1, acc[4]); acc[5] = fmaf(bfhi(v1.z), w1, acc[5]);
    acc[6] = fmaf(bflo(v1.w), w1, acc[6]); acc[7] = fmaf(bfhi(v1.w), w1, acc[7]);
    acc[0] = fmaf(bflo(v2.x), w2, acc[0]); acc[1] = fmaf(bfhi(v2.x), w2, acc[1]);
    acc[2] = fmaf(bflo(v2.y), w2, acc[2]); acc[3] = fmaf(bfhi(v2.y), w2, acc[3]);
    acc[4] = fmaf(bflo(v2.z), w2, acc[4]); acc[5] = fmaf(bfhi(v2.z), w2, acc[5]);
    acc[6] = fmaf(bflo(v2.w), w2, acc[6]); acc[7] = fmaf(bfhi(v2.w), w2, acc[7]);
    acc[0] = fmaf(bflo(v3.x), w3, acc[0]); acc[1] = fmaf(bfhi(v3.x), w3, acc[1]);
    acc[2] = fmaf(bflo(v3.y), w3, acc[2]); acc[3] = fmaf(bfhi(v3.y), w3, acc[3]);
    acc[4] = fmaf(bflo(v3.z), w3, acc[4]); acc[5] = fmaf(bfhi(v3.z), w3, acc[5]);
    acc[6] = fmaf(bflo(v3.w), w3, acc[6]); acc[7] = fmaf(bfhi(v3.w), w3, acc[7]);
  }
  for (; j + 8 <= len; j += 8) {
    unsigned int e0 = ep[j + grp];
    unsigned int e1 = ep[j + 4 + grp];
    uint4 v0 = h4[(size_t)(e0 & 0x1FFFFu) * 16 + c8];
    uint4 v1 = h4[(size_t)(e1 & 0x1FFFFu) * 16 + c8];
    float w0 = (float)(e0 >> 17) * dq;
    float w1 = (float)(e1 >> 17) * dq;
    acc[0] = fmaf(bflo(v0.x), w0, acc[0]); acc[1] = fmaf(bfhi(v0.x), w0, acc[1]);
    acc[2] = fmaf(bflo(v0.y), w0, acc[2]); acc[3] = fmaf(bfhi(v0.y), w0, acc[3]);
    acc[4] = fmaf(bflo(v0.z), w0, acc[4]); acc[5] = fmaf(bfhi(v0.z), w0, acc[5]);
    acc[6] = fmaf(bflo(v0.w), w0, acc[6]); acc[7] = fmaf(bfhi(v0.w), w0, acc[7]);
    acc[0] = fmaf(bflo(v1.x), w1, acc[0]); acc[1] = fmaf(bfhi(v1.x), w1, acc[1]);
    acc[2] = fmaf(bflo(v1.y), w1, acc[2]); acc[3] = fmaf(bfhi(v1.y), w1, acc[3]);
    acc[4] = fmaf(bflo(v1.z), w1, acc[4]); acc[5] = fmaf(bfhi(v1.z), w1, acc[5]);
    acc[6] = fmaf(bflo(v1.w), w1, acc[6]); acc[7] = fmaf(bfhi(v1.w), w1, acc[7]);
  }
  for (; j < len; j += 4) {
    int jj = j + grp;
    unsigned int e = (jj < len) ? ep[jj] : 0u;
    uint4 v = h4[(size_t)(e & 0x1FFFFu) * 16 + c8];
    float w = (float)(e >> 17) * dq;
    acc[0] = fmaf(bflo(v.x), w, acc[0]); acc[1] = fmaf(bfhi(v.x), w, acc[1]);
    acc[2] = fmaf(bflo(v.y), w, acc[2]); acc[3] = fmaf(bfhi(v.y), w, acc[3]);
    acc[4] = fmaf(bflo(v.z), w, acc[4]); acc[5] = fmaf(bfhi(v.z), w, acc[5]);
    acc[6] = fmaf(bflo(v.w), w, acc[6]); acc[7] = fmaf(bfhi(v.w), w, acc[7]);
  }

#pragma unroll
  for (int k = 0; k < 8; ++k) {
    acc[k] += __shfl_xor(acc[k], 16);
    acc[k] += __shfl_xor(acc[k], 32);
  }

  __shared__ float sm[2][16][128];
  if (lane < 16) {
    if (active) {
      uint4 o;
      o.x = pack2bf(acc[0], acc[1]);
      o.y = pack2bf(acc[2], acc[3]);
      o.z = pack2bf(acc[4], acc[5]);
      o.w = pack2bf(acc[6], acc[7]);
      ((uint4*)agg)[(size_t)row * 16 + c8] = o;  // 128 bf16 = 16 uint4 per row
    }
#pragma unroll
    for (int k = 0; k < 8; ++k) {
      float a = acc[k];
      sm[0][wv][c8 * 8 + k] = a;
      sm[1][wv][c8 * 8 + k] = a * a;
    }
  }
  __syncthreads();
  int tid = threadIdx.x;
  int slab = (blockIdx.x & 63) * 256;
  if (tid < 128) {
    float s = 0.f;
#pragma unroll
    for (int w = 0; w < 16; ++w) s += sm[0][w][tid];
    atomicAdd(&bnsumP[slab + tid], s);
  } else if (tid < 256) {
    int c = tid - 128;
    float s = 0.f;
#pragma unroll
    for (int w = 0; w < 16; ++w) s += sm[1][w][c];
    atomicAdd(&bnsumP[slab + 128 + c], s);
  }
}

// ---------------- fused mean-pool (BN computed in-prologue) + head MLP ----------------
__global__ void k_poolhead(const unsigned int* __restrict__ aggd, const float* __restrict__ bnIn,
                           const float* __restrict__ gamma, const float* __restrict__ beta,
                           const int* __restrict__ batch, const float* __restrict__ HW1,
                           const float* __restrict__ Hb1, const float* __restrict__ HW2,
                           const float* __restrict__ Hb2, float* __restrict__ out, int n) {
  __shared__ float bsc[128], bsh[128];
  {
    __shared__ float red[256];
    int tid = threadIdx.x;
    int which = tid >> 7, c = tid & 127;
    float s = 0.f;
    for (int k = 0; k < 64; ++k) s += bnIn[k * 256 + which * 128 + c];
    red[tid] = s;
    __syncthreads();
    if (tid < 128) {
      float invn = 1.0f / (float)n;
      float mu  = red[tid] * invn;
      float var = fmaxf(red[128 + tid] * invn - mu * mu, 0.f);
      float sc  = gamma[tid] * rsqrtf(var + BN_EPS);
      bsc[tid] = sc;
      bsh[tid] = fmaf(-mu, sc, beta[tid]);
    }
    __syncthreads();
  }
  int g = blockIdx.x;
  int wv = threadIdx.x >> 6, t = threadIdx.x & 63;
  int lo = 0, hi = n;
  while (lo < hi) { int mid = (lo + hi) >> 1; if (batch[mid] < g) lo = mid + 1; else hi = mid; }
  int s = lo;
  lo = 0; hi = n;
  int g1 = g + 1;
  while (lo < hi) { int mid = (lo + hi) >> 1; if (batch[mid] < g1) lo = mid + 1; else hi = mid; }
  int e = lo;

  // widened: uint2 per thread (4 cols), 2 rows per wave-iter
  int c16 = t & 31;              // col quad 0..31 -> cols 4*c16..+3
  int rpar = t >> 5;             // row parity within wave
  float sc0 = bsc[4 * c16], sc1 = bsc[4 * c16 + 1];
  float sc2 = bsc[4 * c16 + 2], sc3 = bsc[4 * c16 + 3];
  float sh0 = bsh[4 * c16], sh1 = bsh[4 * c16 + 1];
  float sh2 = bsh[4 * c16 + 2], sh3 = bsh[4 * c16 + 3];
  float a0 = 0.f, a1 = 0.f, a2 = 0.f, a3 = 0.f;
  for (int i = s + wv * 2 + rpar; i < e; i += 8) {
    uint2 u = ((const uint2*)aggd)[(size_t)i * 32 + c16];
    a0 += fmaxf(fmaf(bflo(u.x), sc0, sh0), 0.f);
    a1 += fmaxf(fmaf(bfhi(u.x), sc1, sh1), 0.f);
    a2 += fmaxf(fmaf(bflo(u.y), sc2, sh2), 0.f);
    a3 += fmaxf(fmaf(bfhi(u.y), sc3, sh3), 0.f);
  }
  a0 += __shfl_xor(a0, 32);
  a1 += __shfl_xor(a1, 32);
  a2 += __shfl_xor(a2, 32);
  a3 += __shfl_xor(a3, 32);
  __shared__ float pp[4][128];
  if (t < 32) {
    pp[wv][4 * c16]     = a0;
    pp[wv][4 * c16 + 1] = a1;
    pp[wv][4 * c16 + 2] = a2;
    pp[wv][4 * c16 + 3] = a3;
  }
  __syncthreads();
  if (wv == 0) {
    float inv = 1.0f / fmaxf((float)(e - s), 1.f);
    float p0 = (pp[0][2 * t] + pp[1][2 * t] + pp[2][2 * t] + pp[3][2 * t]) * inv;
    float p1 = (pp[0][2 * t + 1] + pp[1][2 * t + 1] + pp[2][2 * t + 1] + pp[3][2 * t + 1]) * inv;
    pp[0][2 * t] = p0;
    pp[0][2 * t + 1] = p1;
    float acc = Hb1[t];
    for (int k = 0; k < 128; ++k) acc = fmaf(pp[0][k], HW1[k * 64 + t], acc);
    float v = fmaxf(acc, 0.f) * HW2[t];
    for (int off = 32; off > 0; off >>= 1) v += __shfl_down(v, off);
    if (t == 0) out[g] = v + Hb2[0];
  }
}

extern "C" void kernel_launch(void* const* d_in, const int* in_sizes, int n_in,
                              void* d_out, int out_size, void* d_ws, size_t ws_size,
                              hipStream_t stream) {
  const int F_IN = 30, H = 128;
  const float* x   = (const float*)d_in[0];
  const int* eidx  = (const int*)d_in[1];
  const int* batch = (const int*)d_in[2];
  const int N = in_sizes[0] / F_IN;
  const int E = in_sizes[1] / 2;
  const int G = out_size;
  const int* srcp = eidx;
  const int* dstp = eidx + E;
  const float* HW1 = (const float*)d_in[15];
  const float* Hb1 = (const float*)d_in[16];
  const float* HW2 = (const float*)d_in[17];
  const float* Hb2 = (const float*)d_in[18];
  float* outp = (float*)d_out;

  const int Npad = (N + 127) & ~127;
  size_t nh = (size_t)Npad * H;
  const int NB = (N + 255) >> BSH;
  const int CAP = ((E / NB) * 3) / 2 + 128;
  const int NBpad = (NB + 63) & ~63;

  // workspace layout (bf16 unless noted)
  unsigned short* bufH = (unsigned short*)d_ws;      // Npad*128 (gemm out h)
  unsigned short* bufX = bufH + nh;                  // Npad*128 (agg; sedge staging aliases)
  unsigned short* xbf  = bufX + nh;                  // Npad*32 (x0 bf16)
  unsigned short* G0   = xbf + (size_t)Npad * 32;    // Npad*32 (layer-0 gather out)
  float* dinv = (float*)(G0 + (size_t)Npad * 32);    // N (f32)
  int*   cnt    = (int*)(dinv + N);                  // N
  int*   startv = cnt + N;                           // N
  int*   gcur   = startv + N;                        // NBpad  [zeroed]
  float* bnsumP = (float*)(gcur + NBpad);            // 3*64*256 [zeroed]
  unsigned short* Wt0 = (unsigned short*)(bnsumP + 3 * 64 * 256);  // 128*32
  unsigned short* Wt1 = Wt0 + 128 * 32;                      // 128*128
  unsigned short* Wt2 = Wt1 + 128 * 128;                     // 128*128
  unsigned int* elist = (unsigned int*)(Wt2 + 128 * 128 + 64);  // NB*CAP (4B)
  uint2* sedge = (uint2*)bufX;  // staging aliases agg buffer (dead until L0 gemm writes it)

  hipMemsetAsync(gcur, 0, ((size_t)NBpad + 3 * 64 * 256) * sizeof(int), stream);

  // ---- binned CSR build + all conversions (merged, overlapping) ----
  const int BB = (E + 8191) / 8192;
  const int TT = 36864 + N * 32;
  const int CV = (TT + 1023) >> 10;
  k_prep<<<BB + CV, 256, 0, stream>>>(srcp, dstp, gcur, sedge, NB, CAP, E, BB,
                                      x, (const float*)d_in[3], (const float*)d_in[7],
                                      (const float*)d_in[11], xbf, Wt0, Wt1, Wt2, N);
  k_csr1<<<NB, 1024, 0, stream>>>(sedge, gcur, startv, cnt, dinv, CAP, N);
  k_csr2<<<NB, 1024, 0, stream>>>(sedge, gcur, startv, dinv, elist, CAP, N);

  const float* b0  = (const float*)d_in[4];
  const float* gm0 = (const float*)d_in[5];
  const float* bt0 = (const float*)d_in[6];
  const float* b1  = (const float*)d_in[8];
  const float* gm1 = (const float*)d_in[9];
  const float* bt1 = (const float*)d_in[10];
  const float* b2  = (const float*)d_in[12];
  const float* gm2 = (const float*)d_in[13];
  const float* bt2 = (const float*)d_in[14];

  float* slab0 = bnsumP;
  float* slab1 = bnsumP + (size_t)1 * 64 * 256;
  float* slab2 = bnsumP + (size_t)2 * 64 * 256;

  // ---- layer 0 (swapped): gather on x (64 B rows), then gemm with bias+stats ----
  k_gather0<<<(N + 15) / 16, 1024, 0, stream>>>(elist, startv, cnt, dinv,
                                                (const uint4*)xbf, (unsigned int*)G0, N);
  k_gemm_mfma<<<Npad / 128, 256, 0, stream>>>(G0, Wt0, nullptr, nullptr, nullptr, 0,
                                              b0, slab0, 1, bufX, N, 32);

  // ---- layer 1: gemm (BN0 in-prologue) -> gather (bias+stats into slab1) ----
  k_gemm_mfma<<<Npad / 128, 256, 0, stream>>>(bufX, Wt1, slab0, gm0, bt0, 1,
                                              nullptr, nullptr, 0, bufH, N, 128);
  k_gather<<<(N + 15) / 16, 1024, 0, stream>>>(elist, startv, cnt, dinv,
                                               (const uint4*)bufH, b1,
                                               (unsigned int*)bufX, slab1, N);

  // ---- layer 2: gemm (BN1 in-prologue) -> gather (bias+stats into slab2) ----
  k_gemm_mfma<<<Npad / 128, 256, 0, stream>>>(bufX, Wt2, slab1, gm1, bt1, 1,
                                              nullptr, nullptr, 0, bufH, N, 128);
  k_gather<<<(N + 15) / 16, 1024, 0, stream>>>(elist, startv, cnt, dinv,
                                               (const uint4*)bufH, b2,
                                               (unsigned int*)bufX, slab2, N);

  // fused pool (layer-2 BN in-prologue + ReLU) + head
  k_poolhead<<<G, 256, 0, stream>>>((const unsigned int*)bufX, slab2, gm2, bt2, batch,
                                    HW1, Hb1, HW2, Hb2, outp, N);
}

// Round 9
// 418.103 us; speedup vs baseline: 1.0608x; 1.0608x over previous
//
#include <hip/hip_runtime.h>

#define BN_EPS 1e-5f
#define BSH 8  // 256 dsts per bucket

typedef __attribute__((ext_vector_type(8))) short bf16x8;
typedef __attribute__((ext_vector_type(4))) float f32x4;

__device__ inline float bfhi(unsigned int v) { return __uint_as_float(v & 0xFFFF0000u); }
__device__ inline float bflo(unsigned int v) { return __uint_as_float(v << 16); }
__device__ inline unsigned short f2bf(float f) {
  unsigned int u = __float_as_uint(f);
  u += 0x7FFFu + ((u >> 16) & 1u);  // RNE
  return (unsigned short)(u >> 16);
}
__device__ inline unsigned int pack2bf(float lo, float hi) {
  return (unsigned int)f2bf(lo) | ((unsigned int)f2bf(hi) << 16);
}

// ---------------- binned CSR build + input conversions (merged grid) ----------------
__global__ void k_prep(const int* __restrict__ src, const int* __restrict__ dst,
                       int* __restrict__ gcur, uint2* __restrict__ sedge,
                       int NB, int CAP, int E, int BB,
                       const float* __restrict__ x, const float* __restrict__ W0,
                       const float* __restrict__ W1, const float* __restrict__ W2,
                       unsigned short* __restrict__ xb, unsigned short* __restrict__ Wt0,
                       unsigned short* __restrict__ Wt1, unsigned short* __restrict__ Wt2,
                       int n) {
  if ((int)blockIdx.x < BB) {
    // ---- bucket part: localized sedge writes (bucket-contiguous) ----
    __shared__ int lh[512], rb[512];
    int tid = threadIdx.x;
    for (int i = tid; i < NB; i += 256) lh[i] = 0;
    __syncthreads();
    int base = blockIdx.x * 8192;
    int lim = min(8192, E - base);
    for (int i = tid; i < lim; i += 256)
      atomicAdd(&lh[dst[base + i] >> BSH], 1);
    __syncthreads();
    for (int i = tid; i < NB; i += 256) {
      int c = lh[i];
      rb[i] = c ? atomicAdd(&gcur[i], c) : 0;
      lh[i] = 0;
    }
    __syncthreads();
    for (int i = tid; i < lim; i += 256) {
      int d = dst[base + i];
      int s = src[base + i];
      int b = d >> BSH;
      int pos = rb[b] + atomicAdd(&lh[b], 1);
      if (pos < CAP) {
        uint2 v; v.x = (unsigned int)s; v.y = (unsigned int)d;
        sedge[(size_t)b * CAP + pos] = v;
      }
    }
  } else {
    // ---- conversion part (4 elems/thread) ----
    int t0 = (((int)blockIdx.x - BB) * 256 + (int)threadIdx.x) * 4;
#pragma unroll
    for (int u = 0; u < 4; ++u) {
      int t = t0 + u;
      if (t < 4096) {                       // Wt0 [128][32] <- W0 [30][128]
        int nn = t >> 5, k = t & 31;
        Wt0[t] = f2bf(k < 30 ? W0[k * 128 + nn] : 0.f);
      } else if (t < 20480) {               // Wt1 [128][128]
        int i = t - 4096; int nn = i >> 7, k = i & 127;
        Wt1[i] = f2bf(W1[k * 128 + nn]);
      } else if (t < 36864) {               // Wt2
        int i = t - 20480; int nn = i >> 7, k = i & 127;
        Wt2[i] = f2bf(W2[k * 128 + nn]);
      } else {                              // xbf [n][32] <- x [n][30]
        int i = t - 36864;
        if (i < n * 32) {
          int row = i >> 5, c = i & 31;
          xb[i] = f2bf(c < 30 ? x[row * 30 + c] : 0.f);
        }
      }
    }
  }
}

// 1024 threads/block: 4x stream parallelism on the ~391-block grid
__global__ void k_csr1(const uint2* __restrict__ sedge, const int* __restrict__ gcur,
                       int* __restrict__ startv, int* __restrict__ cnt,
                       float* __restrict__ dinv, int CAP, int n) {
  int b = blockIdx.x, tid = threadIdx.x;
  __shared__ int h[256], sc[256];
  if (tid < 256) h[tid] = 0;
  __syncthreads();
  int cb = gcur[b]; if (cb > CAP) cb = CAP;
  const uint2* sd = sedge + (size_t)b * CAP;
  for (int i = tid; i < cb; i += 1024) atomicAdd(&h[sd[i].y & 255], 1);
  __syncthreads();
  if (tid < 256) sc[tid] = h[tid];
  __syncthreads();
  for (int o = 1; o < 256; o <<= 1) {
    int t = (tid < 256 && tid >= o) ? sc[tid - o] : 0;
    __syncthreads();
    if (tid < 256) sc[tid] += t;
    __syncthreads();
  }
  if (tid < 256) {
    int gd = (b << BSH) + tid;
    if (gd < n) {
      int v = h[tid];
      startv[gd] = b * CAP + (sc[tid] - v);
      cnt[gd] = v;
      dinv[gd] = rsqrtf((float)v + 1.0f);
    }
  }
}

// elist entry: src (17 bits) | round(dinv[src]*32767) (15 bits); 1024 threads
__global__ void k_csr2(const uint2* __restrict__ sedge, const int* __restrict__ gcur,
                       const int* __restrict__ startv, const float* __restrict__ dinv,
                       unsigned int* __restrict__ elist, int CAP, int n) {
  int b = blockIdx.x, tid = threadIdx.x;
  __shared__ int cur[256];
  if (tid < 256) {
    int gd = (b << BSH) + tid;
    cur[tid] = (gd < n) ? startv[gd] : 0;
  }
  __syncthreads();
  int cb = gcur[b]; if (cb > CAP) cb = CAP;
  const uint2* sd = sedge + (size_t)b * CAP;
  for (int i = tid; i < cb; i += 1024) {
    uint2 e = sd[i];
    int pos = atomicAdd(&cur[e.y & 255], 1);
    unsigned int u = (unsigned int)(dinv[e.x] * 32767.0f + 0.5f);
    elist[pos] = e.x | (u << 17);
  }
}

// ---------------- layer-0 gather on x [n,32] bf16 (64 B rows); 4 rows/block ----------------
__global__ void k_gather0(const unsigned int* __restrict__ elist, const int* __restrict__ start,
                          const int* __restrict__ cnt, const float* __restrict__ dinv,
                          const uint4* __restrict__ x4,  // [n,4] uint4 (row = 32 bf16)
                          unsigned int* __restrict__ G0, int n) {
  int lane = threadIdx.x & 63;
  int wv   = threadIdx.x >> 6;
  int grp  = lane >> 2;          // 0..15 edge slot
  int q4   = lane & 3;           // col chunk
  int row  = blockIdx.x * 4 + wv;
  bool active = row < n;

  float acc[8];
  float di = 0.f, dq = 0.f;
  int len = 0;
  const unsigned int* ep = elist;
  if (active) {
    di = dinv[row];
    dq = di * (1.0f / 32767.0f);
    len = cnt[row];
    ep = elist + start[row];
  }
  {
    float selfw = (grp == 0 && active) ? di * di : 0.f;
    uint4 hv = (grp == 0 && active) ? x4[(size_t)row * 4 + q4] : make_uint4(0, 0, 0, 0);
    acc[0] = bflo(hv.x) * selfw; acc[1] = bfhi(hv.x) * selfw;
    acc[2] = bflo(hv.y) * selfw; acc[3] = bfhi(hv.y) * selfw;
    acc[4] = bflo(hv.z) * selfw; acc[5] = bfhi(hv.z) * selfw;
    acc[6] = bflo(hv.w) * selfw; acc[7] = bfhi(hv.w) * selfw;
  }
  int j = 0;
  for (; j + 32 <= len; j += 32) {
    unsigned int e0 = ep[j + grp];
    unsigned int e1 = ep[j + 16 + grp];
    uint4 v0 = x4[(size_t)(e0 & 0x1FFFFu) * 4 + q4];
    uint4 v1 = x4[(size_t)(e1 & 0x1FFFFu) * 4 + q4];
    float w0 = (float)(e0 >> 17) * dq;
    float w1 = (float)(e1 >> 17) * dq;
    acc[0] = fmaf(bflo(v0.x), w0, acc[0]); acc[1] = fmaf(bfhi(v0.x), w0, acc[1]);
    acc[2] = fmaf(bflo(v0.y), w0, acc[2]); acc[3] = fmaf(bfhi(v0.y), w0, acc[3]);
    acc[4] = fmaf(bflo(v0.z), w0, acc[4]); acc[5] = fmaf(bfhi(v0.z), w0, acc[5]);
    acc[6] = fmaf(bflo(v0.w), w0, acc[6]); acc[7] = fmaf(bfhi(v0.w), w0, acc[7]);
    acc[0] = fmaf(bflo(v1.x), w1, acc[0]); acc[1] = fmaf(bfhi(v1.x), w1, acc[1]);
    acc[2] = fmaf(bflo(v1.y), w1, acc[2]); acc[3] = fmaf(bfhi(v1.y), w1, acc[3]);
    acc[4] = fmaf(bflo(v1.z), w1, acc[4]); acc[5] = fmaf(bfhi(v1.z), w1, acc[5]);
    acc[6] = fmaf(bflo(v1.w), w1, acc[6]); acc[7] = fmaf(bfhi(v1.w), w1, acc[7]);
  }
  for (; j < len; j += 16) {
    int jj = j + grp;
    unsigned int e = (jj < len) ? ep[jj] : 0u;   // e==0 -> w==0, harmless row-0 load
    uint4 v = x4[(size_t)(e & 0x1FFFFu) * 4 + q4];
    float w = (float)(e >> 17) * dq;
    acc[0] = fmaf(bflo(v.x), w, acc[0]); acc[1] = fmaf(bfhi(v.x), w, acc[1]);
    acc[2] = fmaf(bflo(v.y), w, acc[2]); acc[3] = fmaf(bfhi(v.y), w, acc[3]);
    acc[4] = fmaf(bflo(v.z), w, acc[4]); acc[5] = fmaf(bfhi(v.z), w, acc[5]);
    acc[6] = fmaf(bflo(v.w), w, acc[6]); acc[7] = fmaf(bfhi(v.w), w, acc[7]);
  }
#pragma unroll
  for (int k = 0; k < 8; ++k) {
    acc[k] += __shfl_xor(acc[k], 4);
    acc[k] += __shfl_xor(acc[k], 8);
    acc[k] += __shfl_xor(acc[k], 16);
    acc[k] += __shfl_xor(acc[k], 32);
  }
  if (grp == 0 && active) {
    uint4 o;
    o.x = pack2bf(acc[0], acc[1]);
    o.y = pack2bf(acc[2], acc[3]);
    o.z = pack2bf(acc[4], acc[5]);
    o.w = pack2bf(acc[6], acc[7]);
    ((uint4*)G0)[(size_t)row * 4 + q4] = o;  // 32 bf16 = 4 uint4 per row
  }
}

// ---------------- MFMA GEMM: compile-time KP -> full unroll + hoisted loads ----------------
// No fences: bnIn slab was completed by a PREVIOUS kernel on the stream.
template <int KP, bool DOBN, bool DOSTATS>
__global__ void k_gemm_mfma(const unsigned short* __restrict__ A,
                            const unsigned short* __restrict__ Wt,
                            const float* __restrict__ bnIn, const float* __restrict__ gamma,
                            const float* __restrict__ beta,
                            const float* __restrict__ bias, float* __restrict__ bnslab,
                            unsigned short* __restrict__ C, int n) {
  __shared__ float ssc[128], ssh[128];
  if constexpr (DOBN) {
    __shared__ float red[256];
    int tid = threadIdx.x;
    int which = tid >> 7, c = tid & 127;
    float s = 0.f;
    for (int k = 0; k < 64; ++k) s += bnIn[k * 256 + which * 128 + c];
    red[tid] = s;
    __syncthreads();
    if (tid < 128) {
      float invn = 1.0f / (float)n;
      float mu  = red[tid] * invn;
      float var = fmaxf(red[128 + tid] * invn - mu * mu, 0.f);
      float sc  = gamma[tid] * rsqrtf(var + BN_EPS);
      ssc[tid] = sc;
      ssh[tid] = fmaf(-mu, sc, beta[tid]);
    }
    __syncthreads();
  }
  int wave = threadIdx.x >> 6;
  int lane = threadIdx.x & 63;
  int m0 = blockIdx.x * 128 + wave * 32;  // always < Npad; no early return (stats barrier)
  int lm = lane & 15;
  int lq = lane >> 4;

  f32x4 acc[2][8] = {};
  const unsigned short* Arow0 = A + (size_t)(m0 + lm) * KP + lq * 8;
  const unsigned short* Arow1 = Arow0 + (size_t)16 * KP;
  const unsigned short* Bbase = Wt + (size_t)lm * KP + lq * 8;

#pragma unroll
  for (int k0 = 0; k0 < KP; k0 += 32) {
    uint4 ra0 = *(const uint4*)(Arow0 + k0);
    uint4 ra1 = *(const uint4*)(Arow1 + k0);
    bf16x8 a0, a1;
    if constexpr (DOBN) {
      int cb = k0 + lq * 8;
      unsigned int w0 = pack2bf(fmaxf(fmaf(bflo(ra0.x), ssc[cb+0], ssh[cb+0]), 0.f),
                                fmaxf(fmaf(bfhi(ra0.x), ssc[cb+1], ssh[cb+1]), 0.f));
      unsigned int w1 = pack2bf(fmaxf(fmaf(bflo(ra0.y), ssc[cb+2], ssh[cb+2]), 0.f),
                                fmaxf(fmaf(bfhi(ra0.y), ssc[cb+3], ssh[cb+3]), 0.f));
      unsigned int w2 = pack2bf(fmaxf(fmaf(bflo(ra0.z), ssc[cb+4], ssh[cb+4]), 0.f),
                                fmaxf(fmaf(bfhi(ra0.z), ssc[cb+5], ssh[cb+5]), 0.f));
      unsigned int w3 = pack2bf(fmaxf(fmaf(bflo(ra0.w), ssc[cb+6], ssh[cb+6]), 0.f),
                                fmaxf(fmaf(bfhi(ra0.w), ssc[cb+7], ssh[cb+7]), 0.f));
      uint4 pa0 = make_uint4(w0, w1, w2, w3);
      a0 = *(bf16x8*)&pa0;
      unsigned int y0 = pack2bf(fmaxf(fmaf(bflo(ra1.x), ssc[cb+0], ssh[cb+0]), 0.f),
                                fmaxf(fmaf(bfhi(ra1.x), ssc[cb+1], ssh[cb+1]), 0.f));
      unsigned int y1 = pack2bf(fmaxf(fmaf(bflo(ra1.y), ssc[cb+2], ssh[cb+2]), 0.f),
                                fmaxf(fmaf(bfhi(ra1.y), ssc[cb+3], ssh[cb+3]), 0.f));
      unsigned int y2 = pack2bf(fmaxf(fmaf(bflo(ra1.z), ssc[cb+4], ssh[cb+4]), 0.f),
                                fmaxf(fmaf(bfhi(ra1.z), ssc[cb+5], ssh[cb+5]), 0.f));
      unsigned int y3 = pack2bf(fmaxf(fmaf(bflo(ra1.w), ssc[cb+6], ssh[cb+6]), 0.f),
                                fmaxf(fmaf(bfhi(ra1.w), ssc[cb+7], ssh[cb+7]), 0.f));
      uint4 pa1 = make_uint4(y0, y1, y2, y3);
      a1 = *(bf16x8*)&pa1;
    } else {
      a0 = *(bf16x8*)&ra0;
      a1 = *(bf16x8*)&ra1;
    }
#pragma unroll
    for (int t = 0; t < 8; ++t) {
      bf16x8 b = *(const bf16x8*)(Bbase + (size_t)t * 16 * KP + k0);
      acc[0][t] = __builtin_amdgcn_mfma_f32_16x16x32_bf16(a0, b, acc[0][t], 0, 0, 0);
      acc[1][t] = __builtin_amdgcn_mfma_f32_16x16x32_bf16(a1, b, acc[1][t], 0, 0, 0);
    }
  }

#pragma unroll
  for (int h = 0; h < 2; ++h) {
    int rbase = m0 + h * 16 + lq * 4;
#pragma unroll
    for (int t = 0; t < 8; ++t) {
      int col = t * 16 + lm;
      float bv = DOSTATS ? bias[col] : 0.f;
#pragma unroll
      for (int r = 0; r < 4; ++r) {
        int row = rbase + r;
        if (row < n) C[(size_t)row * 128 + col] = f2bf(acc[h][t][r] + bv);
      }
    }
  }

  if constexpr (DOSTATS) {
    __shared__ float sms[4][256];
#pragma unroll
    for (int t = 0; t < 8; ++t) {
      int col = t * 16 + lm;
      float bv = bias[col];
      float s = 0.f, s2 = 0.f;
#pragma unroll
      for (int h = 0; h < 2; ++h) {
        int rbase = m0 + h * 16 + lq * 4;
#pragma unroll
        for (int r = 0; r < 4; ++r) {
          if (rbase + r < n) {
            float v = acc[h][t][r] + bv;
            s += v; s2 = fmaf(v, v, s2);
          }
        }
      }
      s  += __shfl_xor(s, 16);  s  += __shfl_xor(s, 32);
      s2 += __shfl_xor(s2, 16); s2 += __shfl_xor(s2, 32);
      if (lq == 0) { sms[wave][col] = s; sms[wave][128 + col] = s2; }
    }
    __syncthreads();
    int tid = threadIdx.x;
    int slab = (blockIdx.x & 63) * 256;
    float tot = sms[0][tid] + sms[1][tid] + sms[2][tid] + sms[3][tid];
    atomicAdd(&bnslab[slab + tid], tot);
  }
}

// ---------------- CSR gather (layers 1-2), wave-per-row, 16-edge deep batch ----------------
__global__ void k_gather(const unsigned int* __restrict__ elist, const int* __restrict__ start,
                         const int* __restrict__ cnt, const float* __restrict__ dinv,
                         const uint4* __restrict__ h4,  // [n,16] uint4 (row = 128 bf16)
                         const float* __restrict__ bias, unsigned int* __restrict__ agg,
                         float* __restrict__ bnsumP, int n) {
  int lane = threadIdx.x & 63;
  int wv   = threadIdx.x >> 6;
  int grp  = lane >> 4;
  int c8   = lane & 15;
  int row  = blockIdx.x * 4 + wv;
  bool active = row < n;

  float acc[8];
  float di = 0.f, dq = 0.f;
  int len = 0;
  const unsigned int* ep = elist;

  if (active) {
    di = dinv[row];
    dq = di * (1.0f / 32767.0f);
    len = cnt[row];
    ep = elist + start[row];
  }

  {
    float selfw = (grp == 0 && active) ? di * di : 0.f;
    float4 b0 = make_float4(0.f, 0.f, 0.f, 0.f), b1 = b0;
    if (grp == 0 && active) {
      b0 = ((const float4*)bias)[c8 * 2];
      b1 = ((const float4*)bias)[c8 * 2 + 1];
    }
    uint4 hv = active ? h4[(size_t)row * 16 + c8] : make_uint4(0, 0, 0, 0);
    acc[0] = fmaf(bflo(hv.x), selfw, b0.x);
    acc[1] = fmaf(bfhi(hv.x), selfw, b0.y);
    acc[2] = fmaf(bflo(hv.y), selfw, b0.z);
    acc[3] = fmaf(bfhi(hv.y), selfw, b0.w);
    acc[4] = fmaf(bflo(hv.z), selfw, b1.x);
    acc[5] = fmaf(bfhi(hv.z), selfw, b1.y);
    acc[6] = fmaf(bflo(hv.w), selfw, b1.z);
    acc[7] = fmaf(bfhi(hv.w), selfw, b1.w);
  }

  int j = 0;
  for (; j + 16 <= len; j += 16) {
    unsigned int e0 = ep[j + grp];
    unsigned int e1 = ep[j + 4 + grp];
    unsigned int e2 = ep[j + 8 + grp];
    unsigned int e3 = ep[j + 12 + grp];
    uint4 v0 = h4[(size_t)(e0 & 0x1FFFFu) * 16 + c8];
    uint4 v1 = h4[(size_t)(e1 & 0x1FFFFu) * 16 + c8];
    uint4 v2 = h4[(size_t)(e2 & 0x1FFFFu) * 16 + c8];
    uint4 v3 = h4[(size_t)(e3 & 0x1FFFFu) * 16 + c8];
    float w0 = (float)(e0 >> 17) * dq;
    float w1 = (float)(e1 >> 17) * dq;
    float w2 = (float)(e2 >> 17) * dq;
    float w3 = (float)(e3 >> 17) * dq;
    acc[0] = fmaf(bflo(v0.x), w0, acc[0]); acc[1] = fmaf(bfhi(v0.x), w0, acc[1]);
    acc[2] = fmaf(bflo(v0.y), w0, acc[2]); acc[3] = fmaf(bfhi(v0.y), w0, acc[3]);
    acc[4] = fmaf(bflo(v0.z), w0, acc[4]); acc[5] = fmaf(bfhi(v0.z), w0, acc[5]);
    acc[6] = fmaf(bflo(v0.w), w0, acc[6]); acc[7] = fmaf(bfhi(v0.w), w0, acc[7]);
    acc[0] = fmaf(bflo(v1.x), w1, acc[0]); acc[1] = fmaf(bfhi(v1.x), w1, acc[1]);
    acc[2] = fmaf(bflo(v1.y), w1, acc[2]); acc[3] = fmaf(bfhi(v1.y), w1, acc[3]);
    acc[4] = fmaf(bflo(v1.z), w1, acc[4]); acc[5] = fmaf(bfhi(v1.z), w1, acc[5]);
    acc[6] = fmaf(bflo(v1.w), w1, acc[6]); acc[7] = fmaf(bfhi(v1.w), w1, acc[7]);
    acc[0] = fmaf(bflo(v2.x), w2, acc[0]); acc[1] = fmaf(bfhi(v2.x), w2, acc[1]);
    acc[2] = fmaf(bflo(v2.y), w2, acc[2]); acc[3] = fmaf(bfhi(v2.y), w2, acc[3]);
    acc[4] = fmaf(bflo(v2.z), w2, acc[4]); acc[5] = fmaf(bfhi(v2.z), w2, acc[5]);
    acc[6] = fmaf(bflo(v2.w), w2, acc[6]); acc[7] = fmaf(bfhi(v2.w), w2, acc[7]);
    acc[0] = fmaf(bflo(v3.x), w3, acc[0]); acc[1] = fmaf(bfhi(v3.x), w3, acc[1]);
    acc[2] = fmaf(bflo(v3.y), w3, acc[2]); acc[3] = fmaf(bfhi(v3.y), w3, acc[3]);
    acc[4] = fmaf(bflo(v3.z), w3, acc[4]); acc[5] = fmaf(bfhi(v3.z), w3, acc[5]);
    acc[6] = fmaf(bflo(v3.w), w3, acc[6]); acc[7] = fmaf(bfhi(v3.w), w3, acc[7]);
  }
  for (; j + 8 <= len; j += 8) {
    unsigned int e0 = ep[j + grp];
    unsigned int e1 = ep[j + 4 + grp];
    uint4 v0 = h4[(size_t)(e0 & 0x1FFFFu) * 16 + c8];
    uint4 v1 = h4[(size_t)(e1 & 0x1FFFFu) * 16 + c8];
    float w0 = (float)(e0 >> 17) * dq;
    float w1 = (float)(e1 >> 17) * dq;
    acc[0] = fmaf(bflo(v0.x), w0, acc[0]); acc[1] = fmaf(bfhi(v0.x), w0, acc[1]);
    acc[2] = fmaf(bflo(v0.y), w0, acc[2]); acc[3] = fmaf(bfhi(v0.y), w0, acc[3]);
    acc[4] = fmaf(bflo(v0.z), w0, acc[4]); acc[5] = fmaf(bfhi(v0.z), w0, acc[5]);
    acc[6] = fmaf(bflo(v0.w), w0, acc[6]); acc[7] = fmaf(bfhi(v0.w), w0, acc[7]);
    acc[0] = fmaf(bflo(v1.x), w1, acc[0]); acc[1] = fmaf(bfhi(v1.x), w1, acc[1]);
    acc[2] = fmaf(bflo(v1.y), w1, acc[2]); acc[3] = fmaf(bfhi(v1.y), w1, acc[3]);
    acc[4] = fmaf(bflo(v1.z), w1, acc[4]); acc[5] = fmaf(bfhi(v1.z), w1, acc[5]);
    acc[6] = fmaf(bflo(v1.w), w1, acc[6]); acc[7] = fmaf(bfhi(v1.w), w1, acc[7]);
  }
  for (; j < len; j += 4) {
    int jj = j + grp;
    unsigned int e = (jj < len) ? ep[jj] : 0u;
    uint4 v = h4[(size_t)(e & 0x1FFFFu) * 16 + c8];
    float w = (float)(e >> 17) * dq;
    acc[0] = fmaf(bflo(v.x), w, acc[0]); acc[1] = fmaf(bfhi(v.x), w, acc[1]);
    acc[2] = fmaf(bflo(v.y), w, acc[2]); acc[3] = fmaf(bfhi(v.y), w, acc[3]);
    acc[4] = fmaf(bflo(v.z), w, acc[4]); acc[5] = fmaf(bfhi(v.z), w, acc[5]);
    acc[6] = fmaf(bflo(v.w), w, acc[6]); acc[7] = fmaf(bfhi(v.w), w, acc[7]);
  }

#pragma unroll
  for (int k = 0; k < 8; ++k) {
    acc[k] += __shfl_xor(acc[k], 16);
    acc[k] += __shfl_xor(acc[k], 32);
  }

  __shared__ float sm[2][4][128];
  if (lane < 16) {
    if (active) {
      uint4 o;
      o.x = pack2bf(acc[0], acc[1]);
      o.y = pack2bf(acc[2], acc[3]);
      o.z = pack2bf(acc[4], acc[5]);
      o.w = pack2bf(acc[6], acc[7]);
      ((uint4*)agg)[(size_t)row * 16 + c8] = o;  // 128 bf16 = 16 uint4 per row
    }
#pragma unroll
    for (int k = 0; k < 8; ++k) {
      float a = acc[k];
      sm[0][wv][c8 * 8 + k] = a;
      sm[1][wv][c8 * 8 + k] = a * a;
    }
  }
  __syncthreads();
  int tid = threadIdx.x;
  int slab = (blockIdx.x & 63) * 256;
  if (tid < 128) {
    float s = sm[0][0][tid] + sm[0][1][tid] + sm[0][2][tid] + sm[0][3][tid];
    atomicAdd(&bnsumP[slab + tid], s);
  } else {
    int c = tid - 128;
    float s = sm[1][0][c] + sm[1][1][c] + sm[1][2][c] + sm[1][3][c];
    atomicAdd(&bnsumP[slab + 128 + c], s);
  }
}

// ---------------- fused mean-pool (BN computed in-prologue) + head MLP ----------------
__global__ void k_poolhead(const unsigned int* __restrict__ aggd, const float* __restrict__ bnIn,
                           const float* __restrict__ gamma, const float* __restrict__ beta,
                           const int* __restrict__ batch, const float* __restrict__ HW1,
                           const float* __restrict__ Hb1, const float* __restrict__ HW2,
                           const float* __restrict__ Hb2, float* __restrict__ out, int n) {
  __shared__ float bsc[128], bsh[128];
  {
    __shared__ float red[256];
    int tid = threadIdx.x;
    int which = tid >> 7, c = tid & 127;
    float s = 0.f;
    for (int k = 0; k < 64; ++k) s += bnIn[k * 256 + which * 128 + c];
    red[tid] = s;
    __syncthreads();
    if (tid < 128) {
      float invn = 1.0f / (float)n;
      float mu  = red[tid] * invn;
      float var = fmaxf(red[128 + tid] * invn - mu * mu, 0.f);
      float sc  = gamma[tid] * rsqrtf(var + BN_EPS);
      bsc[tid] = sc;
      bsh[tid] = fmaf(-mu, sc, beta[tid]);
    }
    __syncthreads();
  }
  int g = blockIdx.x;
  int wv = threadIdx.x >> 6, t = threadIdx.x & 63;
  int lo = 0, hi = n;
  while (lo < hi) { int mid = (lo + hi) >> 1; if (batch[mid] < g) lo = mid + 1; else hi = mid; }
  int s = lo;
  lo = 0; hi = n;
  int g1 = g + 1;
  while (lo < hi) { int mid = (lo + hi) >> 1; if (batch[mid] < g1) lo = mid + 1; else hi = mid; }
  int e = lo;

  // widened: uint2 per thread (4 cols), 2 rows per wave-iter
  int c16 = t & 31;              // col quad 0..31 -> cols 4*c16..+3
  int rpar = t >> 5;             // row parity within wave
  float sc0 = bsc[4 * c16], sc1 = bsc[4 * c16 + 1];
  float sc2 = bsc[4 * c16 + 2], sc3 = bsc[4 * c16 + 3];
  float sh0 = bsh[4 * c16], sh1 = bsh[4 * c16 + 1];
  float sh2 = bsh[4 * c16 + 2], sh3 = bsh[4 * c16 + 3];
  float a0 = 0.f, a1 = 0.f, a2 = 0.f, a3 = 0.f;
  for (int i = s + wv * 2 + rpar; i < e; i += 8) {
    uint2 u = ((const uint2*)aggd)[(size_t)i * 32 + c16];
    a0 += fmaxf(fmaf(bflo(u.x), sc0, sh0), 0.f);
    a1 += fmaxf(fmaf(bfhi(u.x), sc1, sh1), 0.f);
    a2 += fmaxf(fmaf(bflo(u.y), sc2, sh2), 0.f);
    a3 += fmaxf(fmaf(bfhi(u.y), sc3, sh3), 0.f);
  }
  a0 += __shfl_xor(a0, 32);
  a1 += __shfl_xor(a1, 32);
  a2 += __shfl_xor(a2, 32);
  a3 += __shfl_xor(a3, 32);
  __shared__ float pp[4][128];
  if (t < 32) {
    pp[wv][4 * c16]     = a0;
    pp[wv][4 * c16 + 1] = a1;
    pp[wv][4 * c16 + 2] = a2;
    pp[wv][4 * c16 + 3] = a3;
  }
  __syncthreads();
  if (wv == 0) {
    float inv = 1.0f / fmaxf((float)(e - s), 1.f);
    float p0 = (pp[0][2 * t] + pp[1][2 * t] + pp[2][2 * t] + pp[3][2 * t]) * inv;
    float p1 = (pp[0][2 * t + 1] + pp[1][2 * t + 1] + pp[2][2 * t + 1] + pp[3][2 * t + 1]) * inv;
    pp[0][2 * t] = p0;
    pp[0][2 * t + 1] = p1;
    float acc = Hb1[t];
    for (int k = 0; k < 128; ++k) acc = fmaf(pp[0][k], HW1[k * 64 + t], acc);
    float v = fmaxf(acc, 0.f) * HW2[t];
    for (int off = 32; off > 0; off >>= 1) v += __shfl_down(v, off);
    if (t == 0) out[g] = v + Hb2[0];
  }
}

extern "C" void kernel_launch(void* const* d_in, const int* in_sizes, int n_in,
                              void* d_out, int out_size, void* d_ws, size_t ws_size,
                              hipStream_t stream) {
  const int F_IN = 30, H = 128;
  const float* x   = (const float*)d_in[0];
  const int* eidx  = (const int*)d_in[1];
  const int* batch = (const int*)d_in[2];
  const int N = in_sizes[0] / F_IN;
  const int E = in_sizes[1] / 2;
  const int G = out_size;
  const int* srcp = eidx;
  const int* dstp = eidx + E;
  const float* HW1 = (const float*)d_in[15];
  const float* Hb1 = (const float*)d_in[16];
  const float* HW2 = (const float*)d_in[17];
  const float* Hb2 = (const float*)d_in[18];
  float* outp = (float*)d_out;

  const int Npad = (N + 127) & ~127;
  size_t nh = (size_t)Npad * H;
  const int NB = (N + 255) >> BSH;
  const int CAP = ((E / NB) * 3) / 2 + 128;
  const int NBpad = (NB + 63) & ~63;

  // workspace layout (bf16 unless noted)
  unsigned short* bufH = (unsigned short*)d_ws;      // Npad*128 (gemm out h)
  unsigned short* bufX = bufH + nh;                  // Npad*128 (agg; sedge staging aliases)
  unsigned short* xbf  = bufX + nh;                  // Npad*32 (x0 bf16)
  unsigned short* G0   = xbf + (size_t)Npad * 32;    // Npad*32 (layer-0 gather out)
  float* dinv = (float*)(G0 + (size_t)Npad * 32);    // N (f32)
  int*   cnt    = (int*)(dinv + N);                  // N
  int*   startv = cnt + N;                           // N
  int*   gcur   = startv + N;                        // NBpad  [zeroed]
  float* bnsumP = (float*)(gcur + NBpad);            // 3*64*256 [zeroed]
  unsigned short* Wt0 = (unsigned short*)(bnsumP + 3 * 64 * 256);  // 128*32
  unsigned short* Wt1 = Wt0 + 128 * 32;                      // 128*128
  unsigned short* Wt2 = Wt1 + 128 * 128;                     // 128*128
  unsigned int* elist = (unsigned int*)(Wt2 + 128 * 128 + 64);  // NB*CAP (4B)
  uint2* sedge = (uint2*)bufX;  // staging aliases agg buffer (dead until L0 gemm writes it)

  hipMemsetAsync(gcur, 0, ((size_t)NBpad + 3 * 64 * 256) * sizeof(int), stream);

  // ---- binned CSR build + all conversions (merged, overlapping) ----
  const int BB = (E + 8191) / 8192;
  const int TT = 36864 + N * 32;
  const int CV = (TT + 1023) >> 10;
  k_prep<<<BB + CV, 256, 0, stream>>>(srcp, dstp, gcur, sedge, NB, CAP, E, BB,
                                      x, (const float*)d_in[3], (const float*)d_in[7],
                                      (const float*)d_in[11], xbf, Wt0, Wt1, Wt2, N);
  k_csr1<<<NB, 1024, 0, stream>>>(sedge, gcur, startv, cnt, dinv, CAP, N);
  k_csr2<<<NB, 1024, 0, stream>>>(sedge, gcur, startv, dinv, elist, CAP, N);

  const float* b0  = (const float*)d_in[4];
  const float* gm0 = (const float*)d_in[5];
  const float* bt0 = (const float*)d_in[6];
  const float* b1  = (const float*)d_in[8];
  const float* gm1 = (const float*)d_in[9];
  const float* bt1 = (const float*)d_in[10];
  const float* b2  = (const float*)d_in[12];
  const float* gm2 = (const float*)d_in[13];
  const float* bt2 = (const float*)d_in[14];

  float* slab0 = bnsumP;
  float* slab1 = bnsumP + (size_t)1 * 64 * 256;
  float* slab2 = bnsumP + (size_t)2 * 64 * 256;

  // ---- layer 0 (swapped): gather on x (64 B rows), then gemm with bias+stats ----
  k_gather0<<<(N + 3) / 4, 256, 0, stream>>>(elist, startv, cnt, dinv,
                                             (const uint4*)xbf, (unsigned int*)G0, N);
  k_gemm_mfma<32, false, true><<<Npad / 128, 256, 0, stream>>>(
      G0, Wt0, nullptr, nullptr, nullptr, b0, slab0, bufX, N);

  // ---- layer 1: gemm (BN0 in-prologue) -> gather (bias+stats into slab1) ----
  k_gemm_mfma<128, true, false><<<Npad / 128, 256, 0, stream>>>(
      bufX, Wt1, slab0, gm0, bt0, nullptr, nullptr, bufH, N);
  k_gather<<<(N + 3) / 4, 256, 0, stream>>>(elist, startv, cnt, dinv,
                                            (const uint4*)bufH, b1,
                                            (unsigned int*)bufX, slab1, N);

  // ---- layer 2: gemm (BN1 in-prologue) -> gather (bias+stats into slab2) ----
  k_gemm_mfma<128, true, false><<<Npad / 128, 256, 0, stream>>>(
      bufX, Wt2, slab1, gm1, bt1, nullptr, nullptr, bufH, N);
  k_gather<<<(N + 3) / 4, 256, 0, stream>>>(elist, startv, cnt, dinv,
                                            (const uint4*)bufH, b2,
                                            (unsigned int*)bufX, slab2, N);

  // fused pool (layer-2 BN in-prologue + ReLU) + head
  k_poolhead<<<G, 256, 0, stream>>>((const unsigned int*)bufX, slab2, gm2, bt2, batch,
                                    HW1, Hb1, HW2, Hb2, outp, N);
}